// Round 13
// baseline (263.103 us; speedup 1.0000x reference)
//
#include <hip/hip_runtime.h>

#define NN 100000
#define NE 640000
#define IND 128
#define HD 256
#define NC 40
#define MT 64      // nodes per block in MLP (4 waves)
#define HPAD 264   // h_s row stride (bf16 elems)
#define LPAD 52    // l_s row stride (f32)
#define NB 196     // dst buckets (512 rows each): ceil(100000/512)
#define CAP 5120   // bucket capacity (mean 3265, +32 sigma)
#define EPB 2500   // edges per bin_k block (256*2500 = NE exactly)
#define SGRID 2048 // persistent spmm blocks (8/CU, 32 waves/CU resident)

typedef unsigned short u16;
typedef unsigned int u32;
typedef __attribute__((ext_vector_type(8))) short bf16x8;
typedef __attribute__((ext_vector_type(4))) float f32x4;

__device__ __forceinline__ float bf2f(u16 u) {
    union { u32 i; float f; } c; c.i = ((u32)u) << 16; return c.f;
}
__device__ __forceinline__ u16 f2bf(float f) {
    union { float f; u32 i; } c; c.f = f;
    u32 i = c.i;
    return (u16)((i + 0x7FFFu + ((i >> 16) & 1u)) >> 16); // RNE
}
__device__ __forceinline__ float rfl_f(float v) {
    return __int_as_float(__builtin_amdgcn_readfirstlane(__float_as_int(v)));
}
__device__ __forceinline__ int wave_incl_scan(int v, int lane) {
    #pragma unroll
    for (int off = 1; off < 64; off <<= 1) {
        int t = __shfl_up(v, off);
        if (lane >= off) v += t;
    }
    return v;
}

// P1: W1/W2 fragment packing + gcur zeroing (replaces the memset dispatch).
__global__ __launch_bounds__(256) void prep_k(
    const float* __restrict__ W1, const float* __restrict__ W2,
    u16* __restrict__ pw1, u16* __restrict__ pw2, int* __restrict__ gcur)
{
    const int gtid = blockIdx.x * 256 + threadIdx.x;
    if (gtid < NB) gcur[gtid] = 0;
    if (gtid < 4096) {                       // W1 [128x256] -> [ct16][ks4][lane64][j8]
        int lane = gtid & 63, fid = gtid >> 6;
        int ks = fid & 3, ct = fid >> 2;
        int quad = lane >> 4, m = lane & 15;
        int n = ct * 16 + m;
        u16* o = pw1 + (size_t)gtid * 8;
        #pragma unroll
        for (int j = 0; j < 8; j++) o[j] = f2bf(W1[(ks * 32 + quad * 8 + j) * HD + n]);
    } else if (gtid < 4096 + 1536) {         // W2 [256x40] -> [ct3][ks8][lane64][j8] pad 48
        int idx = gtid - 4096;
        int lane = idx & 63, fid = idx >> 6;
        int ks = fid & 7, ct = fid >> 3;
        int quad = lane >> 4, m = lane & 15;
        int n = ct * 16 + m;
        u16* o = pw2 + (size_t)idx * 8;
        #pragma unroll
        for (int j = 0; j < 8; j++)
            o[j] = (n < NC) ? f2bf(W2[(ks * 32 + quad * 8 + j) * NC + n]) : (u16)0;
    }
}

// P2: bucket-binning pass. 256 blocks x 2500 edges. LDS-sort edges by
// dst-bucket, reserve per-bucket runs with ONE global atomic per
// (block,bucket), write ~13-word runs (full-line merges in L2).
// Packed edge: bits 0-16 = src (<2^17), bits 17-25 = dst&511.
__global__ __launch_bounds__(256) void bin_k(
    const int* __restrict__ src, const int* __restrict__ dst,
    int* __restrict__ gcur, u32* __restrict__ ebuf)
{
    __shared__ int cnt[NB], cur[NB], rdest[NB];
    __shared__ u32 vals[EPB];
    const int tid = threadIdx.x;
    const int e0 = blockIdx.x * EPB;

    if (tid < NB) cnt[tid] = 0;
    __syncthreads();
    for (int i = tid; i < EPB; i += 256)
        atomicAdd(&cnt[dst[e0 + i] >> 9], 1);
    __syncthreads();
    if (tid < 64) {                          // exclusive scan of cnt -> cur (wave 0)
        int carry = 0;
        #pragma unroll
        for (int c = 0; c < 4; c++) {
            const int idx = c * 64 + tid;
            const int v = (idx < NB) ? cnt[idx] : 0;
            const int incl = wave_incl_scan(v, tid);
            if (idx < NB) cur[idx] = carry + incl - v;
            carry += __shfl(incl, 63);
        }
    }
    __syncthreads();
    for (int i = tid; i < EPB; i += 256) {   // LDS scatter (bucket-sorted)
        const int s = src[e0 + i], d = dst[e0 + i];
        const int b = d >> 9;
        const int slot = atomicAdd(&cur[b], 1);
        vals[slot] = ((u32)(d & 511) << 17) | (u32)s;
    }
    __syncthreads();
    if (tid < NB) {                          // reserve runs
        const int c = cnt[tid];
        int st = 0;
        if (c > 0) st = atomicAdd(&gcur[tid], c);
        rdest[tid] = (st + c <= CAP) ? st : -1;   // overflow guard (won't trigger)
    }
    __syncthreads();
    if (tid < NB) {                          // copy runs (consecutive stores/line)
        const int c = cnt[tid];
        const int st = rdest[tid];
        if (c > 0 && st >= 0) {
            const int lo = cur[tid] - c;     // cur == end after pass2
            u32* o = ebuf + (size_t)tid * CAP + st;
            for (int k = 0; k < c; k++) o[k] = vals[lo + k];
        }
    }
}

// P3: per-bucket CSR build + FUSED feats->z conversion for this bucket's
// 512 rows (the streaming conversion rides under the histogram/scan/
// compaction latency; kills the standalone conv_k dispatch).
// Block 0 additionally zeroes gather zero-row NN of zF/zA/zB.
__global__ __launch_bounds__(256) void build_k(
    const int* __restrict__ gcur, u32* __restrict__ ebuf,
    int2* __restrict__ rb, float* __restrict__ norm, float* __restrict__ invn,
    const float4* __restrict__ feats4, uint2* __restrict__ zF2,
    uint2* __restrict__ zA2, uint2* __restrict__ zB2)
{
    __shared__ int rowcnt[512], rowoff[512], csum[8];
    __shared__ float normS[512];
    __shared__ u32 evals[CAP];
    const int tid = threadIdx.x;
    const int b = blockIdx.x;
    const int bB = b * CAP;                  // absolute base into ebuf
    const int r0 = b * 512;
    const int nb = min(__builtin_amdgcn_readfirstlane(gcur[b]), CAP);

    if (b == 0 && tid < 96) {                // zero-row NN: 3 bufs x 32 uint2
        const int which = tid >> 5, idx = tid & 31;
        uint2* z = (which == 0) ? zF2 : (which == 1) ? zA2 : zB2;
        z[(size_t)NN * 32 + idx] = make_uint2(0u, 0u);
    }

    rowcnt[tid] = 0; rowcnt[256 + tid] = 0;
    __syncthreads();
    for (int i = tid; i < nb; i += 256) {
        const u32 v = ebuf[bB + i];
        evals[i] = v;
        atomicAdd(&rowcnt[(v >> 17) & 511], 1);
    }
    __syncthreads();
    {                                        // scan 512: 4 waves x 2 chunks + carry
        const int w = tid >> 6, lane = tid & 63;
        #pragma unroll
        for (int r = 0; r < 2; r++) {
            const int c = r * 4 + w;
            const int v = rowcnt[c * 64 + lane];
            const int incl = wave_incl_scan(v, lane);
            rowoff[c * 64 + lane] = incl - v;
            if (lane == 63) csum[c] = incl;
        }
        __syncthreads();
        if (tid == 0) {
            int run = 0;
            #pragma unroll
            for (int c = 0; c < 8; c++) { const int t = csum[c]; csum[c] = run; run += t; }
        }
        __syncthreads();
        #pragma unroll
        for (int r = 0; r < 2; r++) {
            const int c = r * 4 + w;
            rowoff[c * 64 + lane] += csum[c];
        }
    }
    __syncthreads();
    #pragma unroll
    for (int r = 0; r < 2; r++) {            // emit rb / norm / invn (+ normS)
        const int idx = r * 256 + tid;
        const int row = r0 + idx;
        if (row < NN) {
            const int deg = rowcnt[idx];
            const int base = bB + rowoff[idx];
            rb[row] = make_int2(base, base + deg);
            const float dc = fmaxf((float)deg, 1.0f);
            const float nm = rsqrtf(dc);
            norm[row] = nm;
            normS[idx] = nm;
            invn[row] = sqrtf(dc);
        }
    }
    __syncthreads();
    for (int i = tid; i < nb; i += 256) {    // in-place compaction (rowoff as cursor)
        const u32 v = evals[i];
        const int rl = (v >> 17) & 511;
        const int pos = atomicAdd(&rowoff[rl], 1);
        ebuf[bB + pos] = v & 0x1FFFFu;
    }
    // fused conv: this bucket's rows, feats*norm -> bf16 z (coalesced stream)
    const int nrows = min(512, NN - r0);
    const int n4 = nrows * 32;               // float4 per bucket
    const size_t gbase = (size_t)r0 * 32;
    for (int i = tid; i < n4; i += 256) {
        const float4 v = feats4[gbase + i];
        const float n = normS[i >> 5];
        uint2 o;
        o.x = (u32)f2bf(v.x * n) | ((u32)f2bf(v.y * n) << 16);
        o.y = (u32)f2bf(v.z * n) | ((u32)f2bf(v.w * n) << 16);
        zF2[gbase + i] = o;
    }
}

// P5: gather-SpMM — persistent waves, grid-stride over rows. At the
// random-256B-segment service equilibrium (~3.7 TB/s, R6/R7 discriminated:
// more concurrency does NOT help) — structural floor for a uniform graph.
// LAST: ys = 0.25*((zF+zA+zB)*invn + n*a), pre-scaled bf16 for the MLP.
template <int LAST>
__global__ __launch_bounds__(256) void spmm_k(
    const u32* __restrict__ x, u32* __restrict__ xnext,
    const u32* __restrict__ x0, const u32* __restrict__ x1,
    const int2* __restrict__ rb, const int* __restrict__ csr,
    const float* __restrict__ norm, const float* __restrict__ invn)
{
    const int lane = threadIdx.x & 63;
    int wid = (blockIdx.x * 256 + threadIdx.x) >> 6;
    wid = __builtin_amdgcn_readfirstlane(wid);          // wave-uniform
    const int nw = SGRID * 4;                           // total resident waves

    for (int row = wid; row < NN; row += nw) {
        const int2 be = rb[row];
        const int beg = __builtin_amdgcn_readfirstlane(be.x);
        const int end = __builtin_amdgcn_readfirstlane(be.y);
        const float n = rfl_f(norm[row]);

        float a0 = 0.f, a1 = 0.f;
        for (int b = beg; b < end; b += 8) {
            int sN[8];
            #pragma unroll
            for (int j = 0; j < 8; j++) {
                const int ee = b + j;                   // < NB*CAP+64 (padded alloc)
                const int c = csr[ee];                  // uniform s_load
                int s = __builtin_amdgcn_readfirstlane(c);
                if (ee >= end) s = NN;                  // scalar select -> zero-row
                sN[j] = s;
            }
            u32 u[8];
            #pragma unroll
            for (int j = 0; j < 8; j++) {
                const u32* rp = x + ((size_t)sN[j] << 6);   // SGPR base per edge
                u[j] = rp[lane];                            // coalesced 256B row
            }
            #pragma unroll
            for (int j = 0; j < 8; j++) {
                a0 += __int_as_float((int)(u[j] << 16));
                a1 += __int_as_float((int)(u[j] & 0xFFFF0000u));
            }
        }

        const size_t ri = (size_t)row * 64 + lane;
        u32 o;
        if (!LAST) {
            const float n2 = n * n;
            o = (u32)f2bf(a0 * n2) | ((u32)f2bf(a1 * n2) << 16);
        } else {
            const float inv = rfl_f(invn[row]);
            const u32 v0 = x0[ri];
            const u32 v1 = x1[ri];
            const u32 v2 = x[ri];
            const float s0 = (bf2f((u16)(v0 & 0xFFFFu)) + bf2f((u16)(v1 & 0xFFFFu))
                            + bf2f((u16)(v2 & 0xFFFFu))) * inv + a0 * n;
            const float s1 = (bf2f((u16)(v0 >> 16)) + bf2f((u16)(v1 >> 16))
                            + bf2f((u16)(v2 >> 16))) * inv + a1 * n;
            o = (u32)f2bf(s0 * 0.25f) | ((u32)f2bf(s1 * 0.25f) << 16);
        }
        xnext[ri] = o;
    }
}

// P6: MFMA MLP v4 (best measured: 247.0 total) — ct-split layer 1: wave w
// owns ct columns [4w,4w+4), computes them for ALL 64 nodes (4 MFMA per
// weight load). Layer 2: depth-2 ks prefetch. l_s aliases h_s rows
// [16w,16w+16) per wave (reads precede writes in program order; cross-wave
// phases fenced by __syncthreads). v5 (LDS weights, 8 waves/CU) regressed:
// occupancy/TLP carries this kernel, not the weight path.
__global__ __launch_bounds__(256, 4) void mlp_mfma_k(
    const u16* __restrict__ ys, const u16* __restrict__ pw1,
    const float* __restrict__ B1, const u16* __restrict__ pw2,
    const float* __restrict__ B2, float* __restrict__ out, int N)
{
    __shared__ __align__(16) u16 h_s[MT * HPAD];        // 33792 B, l_s aliased in
    const int t = threadIdx.x;
    const int w = t >> 6, lane = t & 63;
    const int quad = lane >> 4, m = lane & 15;
    const int node0 = blockIdx.x * MT;
    float* const lw = (float*)((char*)h_s + (size_t)w * 16 * HPAD * 2); // wave-local l

    // A-fragments for ALL 64 nodes (4 groups of 16)
    bf16x8 av[4][4];                                    // [g][ks], 64 VGPR
    #pragma unroll
    for (int g = 0; g < 4; g++) {
        int node = node0 + g * 16 + m;
        if (node > N - 1) node = N - 1;
        #pragma unroll
        for (int ks = 0; ks < 4; ks++)
            av[g][ks] = *(const bf16x8*)(ys + (size_t)node * IND + ks * 32 + quad * 8);
    }

    // ---- layer 1: wave w -> ct in [4w, 4w+4), depth-2 wb prefetch ----
    const u16* const pwl = pw1 + (size_t)lane * 8;
    const int ct0 = w * 4;
    bf16x8 wb[2][4];
    #pragma unroll
    for (int ks = 0; ks < 4; ks++)
        wb[0][ks] = *(const bf16x8*)(pwl + (size_t)((ct0 * 4 + ks) * 64) * 8);
    #pragma unroll
    for (int ct2 = 0; ct2 < 4; ct2++) {                 // ct2 compile-time: static idx
        const int ct = ct0 + ct2;
        if (ct2 + 1 < 4) {
            #pragma unroll
            for (int ks = 0; ks < 4; ks++)
                wb[(ct2 + 1) & 1][ks] =
                    *(const bf16x8*)(pwl + (size_t)(((ct + 1) * 4 + ks) * 64) * 8);
        }
        const int cs = ct2 & 1;
        f32x4 acc[4];
        #pragma unroll
        for (int g = 0; g < 4; g++) acc[g] = (f32x4){ 0.f, 0.f, 0.f, 0.f };
        #pragma unroll
        for (int ks = 0; ks < 4; ks++) {
            #pragma unroll
            for (int g = 0; g < 4; g++)                 // 4-way independent MFMA per load
                acc[g] = __builtin_amdgcn_mfma_f32_16x16x32_bf16(av[g][ks], wb[cs][ks], acc[g], 0, 0, 0);
        }
        const float b1c = B1[ct * 16 + m];
        #pragma unroll
        for (int g = 0; g < 4; g++) {
            #pragma unroll
            for (int r = 0; r < 4; r++) {
                const float hv = fmaxf(acc[g][r] + b1c, 0.0f);
                h_s[(g * 16 + quad * 4 + r) * HPAD + ct * 16 + m] = f2bf(hv);
            }
        }
    }
    __syncthreads();                                    // h complete (all ct blocks)

    // ---- layer 2: wave w -> node group w, depth-2 prefetch over ks ----
    const u16* const pw2l = pw2 + (size_t)lane * 8;
    f32x4 acc2[3];
    #pragma unroll
    for (int ct = 0; ct < 3; ct++) acc2[ct] = (f32x4){ 0.f, 0.f, 0.f, 0.f };
    bf16x8 w2[3][3];
    #pragma unroll
    for (int ct = 0; ct < 3; ct++) {
        w2[0][ct] = *(const bf16x8*)(pw2l + (size_t)((ct * 8 + 0) * 64) * 8);
        w2[1][ct] = *(const bf16x8*)(pw2l + (size_t)((ct * 8 + 1) * 64) * 8);
    }
    #pragma unroll
    for (int ks = 0; ks < 8; ks++) {                    // ks compile-time: static idx
        if (ks + 2 < 8) {
            const int ns = (ks + 2) % 3;
            #pragma unroll
            for (int ct = 0; ct < 3; ct++)
                w2[ns][ct] = *(const bf16x8*)(pw2l + (size_t)((ct * 8 + ks + 2) * 64) * 8);
        }
        const int cs = ks % 3;
        const bf16x8 a = *(const bf16x8*)&h_s[(w * 16 + m) * HPAD + ks * 32 + quad * 8];
        #pragma unroll
        for (int ct = 0; ct < 3; ct++)
            acc2[ct] = __builtin_amdgcn_mfma_f32_16x16x32_bf16(a, w2[cs][ct], acc2[ct], 0, 0, 0);
    }
    #pragma unroll
    for (int ct = 0; ct < 3; ct++) {
        const int cg = ct * 16 + m;
        const float b2c = (cg < NC) ? B2[cg] : 0.0f;
        #pragma unroll
        for (int r = 0; r < 4; r++)
            lw[(quad * 4 + r) * LPAD + cg] = acc2[ct][r] + b2c;   // after all h reads (lockstep)
    }
    __syncthreads();

    if (t < MT) {
        const int node = node0 + t;
        if (node < N) {
            const float* ln = (const float*)((const char*)h_s + (size_t)(t >> 4) * 16 * HPAD * 2)
                              + (t & 15) * LPAD;
            float mx = -1e30f;
            #pragma unroll
            for (int c = 0; c < NC; c++) mx = fmaxf(mx, ln[c]);
            float s = 0.0f;
            #pragma unroll
            for (int c = 0; c < NC; c++) s += __expf(ln[c] - mx);
            const float lse = mx + __logf(s);
            float4* o = (float4*)(out + (size_t)node * NC);
            #pragma unroll
            for (int c4 = 0; c4 < NC / 4; c4++) {
                float4 v;
                v.x = ln[c4 * 4 + 0] - lse;
                v.y = ln[c4 * 4 + 1] - lse;
                v.z = ln[c4 * 4 + 2] - lse;
                v.w = ln[c4 * 4 + 3] - lse;
                o[c4] = v;
            }
        }
    }
}

extern "C" void kernel_launch(void* const* d_in, const int* in_sizes, int n_in,
                              void* d_out, int out_size, void* d_ws, size_t ws_size,
                              hipStream_t stream) {
    const float* feats = (const float*)d_in[0];
    const int* src = (const int*)d_in[1];
    const int* dst = (const int*)d_in[2];
    const float* W1 = (const float*)d_in[3];
    const float* B1 = (const float*)d_in[4];
    const float* W2 = (const float*)d_in[5];
    const float* B2 = (const float*)d_in[6];
    float* out = (float*)d_out;

    char* base = (char*)d_ws;
    size_t off = 0;
    auto alloc = [&](size_t bytes) -> void* {
        void* p = base + off;
        off += (bytes + 255) & ~(size_t)255;
        return p;
    };
    int*   gcur = (int*)  alloc((size_t)NB * 4);              // zeroed by prep_k
    float* norm = (float*)alloc((size_t)NN * 4);
    float* invn = (float*)alloc((size_t)NN * 4);
    int2*  rb   = (int2*) alloc((size_t)NN * 8);
    u32*   ebuf = (u32*)  alloc(((size_t)NB * CAP + 64) * 4); // bins -> final CSR
    u16*   pw1  = (u16*)  alloc((size_t)16 * 4 * 64 * 8 * 2);
    u16*   pw2  = (u16*)  alloc((size_t)3 * 8 * 64 * 8 * 2);
    u32*   zF   = (u32*)  alloc((size_t)(NN + 1) * (IND / 2) * 4);
    u32*   zA   = (u32*)  alloc((size_t)(NN + 1) * (IND / 2) * 4);
    u32*   zB   = (u32*)  alloc((size_t)(NN + 1) * (IND / 2) * 4);
    u32*   ys   = (u32*)  alloc((size_t)NN * (IND / 2) * 4);

    prep_k<<<22, 256, 0, stream>>>(W1, W2, pw1, pw2, gcur);
    bin_k<<<256, 256, 0, stream>>>(src, dst, gcur, ebuf);
    build_k<<<NB, 256, 0, stream>>>(gcur, ebuf, rb, norm, invn,
                                    (const float4*)feats, (uint2*)zF,
                                    (uint2*)zA, (uint2*)zB);

    spmm_k<0><<<SGRID, 256, 0, stream>>>(zF, zA, nullptr, nullptr, rb, (const int*)ebuf, norm, invn);
    spmm_k<0><<<SGRID, 256, 0, stream>>>(zA, zB, nullptr, nullptr, rb, (const int*)ebuf, norm, invn);
    spmm_k<1><<<SGRID, 256, 0, stream>>>(zB, ys, zF, zA, rb, (const int*)ebuf, norm, invn);

    const int mgrid = (NN + MT - 1) / MT;
    mlp_mfma_k<<<mgrid, 256, 0, stream>>>((const u16*)ys, pw1, B1, pw2, B2, out, NN);
}

// Round 14
// 246.650 us; speedup vs baseline: 1.0667x; 1.0667x over previous
//
#include <hip/hip_runtime.h>

#define NN 100000
#define NE 640000
#define IND 128
#define HD 256
#define NC 40
#define MT 64      // nodes per block in MLP (4 waves)
#define HPAD 264   // h_s row stride (bf16 elems)
#define LPAD 52    // l_s row stride (f32)
#define NB 196     // dst buckets (512 rows each): ceil(100000/512)
#define CAP 5120   // bucket capacity (mean 3265, +32 sigma)
#define EPB 2500   // edges per bin_k block (256*2500 = NE exactly)
#define SGRID 2048 // persistent spmm blocks (8/CU, 32 waves/CU resident)

typedef unsigned short u16;
typedef unsigned int u32;
typedef __attribute__((ext_vector_type(8))) short bf16x8;
typedef __attribute__((ext_vector_type(4))) float f32x4;

__device__ __forceinline__ float bf2f(u16 u) {
    union { u32 i; float f; } c; c.i = ((u32)u) << 16; return c.f;
}
__device__ __forceinline__ u16 f2bf(float f) {
    union { float f; u32 i; } c; c.f = f;
    u32 i = c.i;
    return (u16)((i + 0x7FFFu + ((i >> 16) & 1u)) >> 16); // RNE
}
__device__ __forceinline__ float rfl_f(float v) {
    return __int_as_float(__builtin_amdgcn_readfirstlane(__float_as_int(v)));
}
__device__ __forceinline__ int wave_incl_scan(int v, int lane) {
    #pragma unroll
    for (int off = 1; off < 64; off <<= 1) {
        int t = __shfl_up(v, off);
        if (lane >= off) v += t;
    }
    return v;
}

// P1: W1/W2 fragment packing + gcur zeroing (replaces the memset dispatch).
__global__ __launch_bounds__(256) void prep_k(
    const float* __restrict__ W1, const float* __restrict__ W2,
    u16* __restrict__ pw1, u16* __restrict__ pw2, int* __restrict__ gcur)
{
    const int gtid = blockIdx.x * 256 + threadIdx.x;
    if (gtid < NB) gcur[gtid] = 0;
    if (gtid < 4096) {                       // W1 [128x256] -> [ct16][ks4][lane64][j8]
        int lane = gtid & 63, fid = gtid >> 6;
        int ks = fid & 3, ct = fid >> 2;
        int quad = lane >> 4, m = lane & 15;
        int n = ct * 16 + m;
        u16* o = pw1 + (size_t)gtid * 8;
        #pragma unroll
        for (int j = 0; j < 8; j++) o[j] = f2bf(W1[(ks * 32 + quad * 8 + j) * HD + n]);
    } else if (gtid < 4096 + 1536) {         // W2 [256x40] -> [ct3][ks8][lane64][j8] pad 48
        int idx = gtid - 4096;
        int lane = idx & 63, fid = idx >> 6;
        int ks = fid & 7, ct = fid >> 3;
        int quad = lane >> 4, m = lane & 15;
        int n = ct * 16 + m;
        u16* o = pw2 + (size_t)idx * 8;
        #pragma unroll
        for (int j = 0; j < 8; j++)
            o[j] = (n < NC) ? f2bf(W2[(ks * 32 + quad * 8 + j) * NC + n]) : (u16)0;
    }
}

// P2: bucket-binning pass. 256 blocks x 2500 edges. LDS-sort edges by
// dst-bucket, reserve per-bucket runs with ONE global atomic per
// (block,bucket), write ~13-word runs (full-line merges in L2).
// Packed edge: bits 0-16 = src (<2^17), bits 17-25 = dst&511.
__global__ __launch_bounds__(256) void bin_k(
    const int* __restrict__ src, const int* __restrict__ dst,
    int* __restrict__ gcur, u32* __restrict__ ebuf)
{
    __shared__ int cnt[NB], cur[NB], rdest[NB];
    __shared__ u32 vals[EPB];
    const int tid = threadIdx.x;
    const int e0 = blockIdx.x * EPB;

    if (tid < NB) cnt[tid] = 0;
    __syncthreads();
    for (int i = tid; i < EPB; i += 256)
        atomicAdd(&cnt[dst[e0 + i] >> 9], 1);
    __syncthreads();
    if (tid < 64) {                          // exclusive scan of cnt -> cur (wave 0)
        int carry = 0;
        #pragma unroll
        for (int c = 0; c < 4; c++) {
            const int idx = c * 64 + tid;
            const int v = (idx < NB) ? cnt[idx] : 0;
            const int incl = wave_incl_scan(v, tid);
            if (idx < NB) cur[idx] = carry + incl - v;
            carry += __shfl(incl, 63);
        }
    }
    __syncthreads();
    for (int i = tid; i < EPB; i += 256) {   // LDS scatter (bucket-sorted)
        const int s = src[e0 + i], d = dst[e0 + i];
        const int b = d >> 9;
        const int slot = atomicAdd(&cur[b], 1);
        vals[slot] = ((u32)(d & 511) << 17) | (u32)s;
    }
    __syncthreads();
    if (tid < NB) {                          // reserve runs
        const int c = cnt[tid];
        int st = 0;
        if (c > 0) st = atomicAdd(&gcur[tid], c);
        rdest[tid] = (st + c <= CAP) ? st : -1;   // overflow guard (won't trigger)
    }
    __syncthreads();
    if (tid < NB) {                          // copy runs (consecutive stores/line)
        const int c = cnt[tid];
        const int st = rdest[tid];
        if (c > 0 && st >= 0) {
            const int lo = cur[tid] - c;     // cur == end after pass2
            u32* o = ebuf + (size_t)tid * CAP + st;
            for (int k = 0; k < c; k++) o[k] = vals[lo + k];
        }
    }
}

// P3: per-bucket CSR build. One block per bucket (512 rows): LDS histogram
// + scan -> rb/norm/invn; in-place compaction of ebuf into final CSR.
// Scattered writes land in this block's PRIVATE 20KB region (full-line L2 merge).
__global__ __launch_bounds__(256) void build_k(
    const int* __restrict__ gcur, u32* __restrict__ ebuf,
    int2* __restrict__ rb, float* __restrict__ norm, float* __restrict__ invn)
{
    __shared__ int rowcnt[512], rowoff[512], csum[8];
    __shared__ u32 evals[CAP];
    const int tid = threadIdx.x;
    const int b = blockIdx.x;
    const int bB = b * CAP;                  // absolute base into ebuf
    const int r0 = b * 512;
    const int nb = min(__builtin_amdgcn_readfirstlane(gcur[b]), CAP);

    rowcnt[tid] = 0; rowcnt[256 + tid] = 0;
    __syncthreads();
    for (int i = tid; i < nb; i += 256) {
        const u32 v = ebuf[bB + i];
        evals[i] = v;
        atomicAdd(&rowcnt[(v >> 17) & 511], 1);
    }
    __syncthreads();
    {                                        // scan 512: 4 waves x 2 chunks + carry
        const int w = tid >> 6, lane = tid & 63;
        #pragma unroll
        for (int r = 0; r < 2; r++) {
            const int c = r * 4 + w;
            const int v = rowcnt[c * 64 + lane];
            const int incl = wave_incl_scan(v, lane);
            rowoff[c * 64 + lane] = incl - v;
            if (lane == 63) csum[c] = incl;
        }
        __syncthreads();
        if (tid == 0) {
            int run = 0;
            #pragma unroll
            for (int c = 0; c < 8; c++) { const int t = csum[c]; csum[c] = run; run += t; }
        }
        __syncthreads();
        #pragma unroll
        for (int r = 0; r < 2; r++) {
            const int c = r * 4 + w;
            rowoff[c * 64 + lane] += csum[c];
        }
    }
    __syncthreads();
    #pragma unroll
    for (int r = 0; r < 2; r++) {            // emit rb / norm / invn
        const int idx = r * 256 + tid;
        const int row = r0 + idx;
        if (row < NN) {
            const int deg = rowcnt[idx];
            const int base = bB + rowoff[idx];
            rb[row] = make_int2(base, base + deg);
            const float dc = fmaxf((float)deg, 1.0f);
            norm[row] = rsqrtf(dc);
            invn[row] = sqrtf(dc);
        }
    }
    __syncthreads();
    for (int i = tid; i < nb; i += 256) {    // in-place compaction (rowoff as cursor)
        const u32 v = evals[i];
        const int rl = (v >> 17) & 511;
        const int pos = atomicAdd(&rowoff[rl], 1);
        ebuf[bB + pos] = v & 0x1FFFFu;
    }
}

// P4: feats f32 -> zF = bf16(feats * norm[row]); zeroes gather zero-row NN.
// Standalone at 2048 blocks: streaming needs full-device TLP (R13 lesson —
// fusing this into 196-block build_k ran it at 1.3 TB/s, +16 us).
__global__ __launch_bounds__(256) void conv_k(
    const float4* __restrict__ feats4, const float* __restrict__ norm,
    uint2* __restrict__ zF2, uint2* __restrict__ zA2, uint2* __restrict__ zB2)
{
    const int gtid = blockIdx.x * 256 + threadIdx.x, gsz = gridDim.x * 256;
    if (gtid < 96) {                          // zero-row NN: 3 bufs x 32 uint2
        const int which = gtid >> 5, idx = gtid & 31;
        uint2* b = (which == 0) ? zF2 : (which == 1) ? zA2 : zB2;
        b[(size_t)NN * 32 + idx] = make_uint2(0u, 0u);
    }
    for (int i = gtid; i < NN * (IND / 4); i += gsz) {
        const float4 v = feats4[i];
        const float n = norm[i >> 5];          // 32 float4 per row
        uint2 o;
        o.x = (u32)f2bf(v.x * n) | ((u32)f2bf(v.y * n) << 16);
        o.y = (u32)f2bf(v.z * n) | ((u32)f2bf(v.w * n) << 16);
        zF2[i] = o;
    }
}

// P5: gather-SpMM — persistent waves, grid-stride over rows. At the
// random-256B-segment service equilibrium (~3.7 TB/s, R6/R7 discriminated:
// more concurrency does NOT help) — structural floor for a uniform graph.
// LAST: ys = 0.25*((zF+zA+zB)*invn + n*a), pre-scaled bf16 for the MLP.
template <int LAST>
__global__ __launch_bounds__(256) void spmm_k(
    const u32* __restrict__ x, u32* __restrict__ xnext,
    const u32* __restrict__ x0, const u32* __restrict__ x1,
    const int2* __restrict__ rb, const int* __restrict__ csr,
    const float* __restrict__ norm, const float* __restrict__ invn)
{
    const int lane = threadIdx.x & 63;
    int wid = (blockIdx.x * 256 + threadIdx.x) >> 6;
    wid = __builtin_amdgcn_readfirstlane(wid);          // wave-uniform
    const int nw = SGRID * 4;                           // total resident waves

    for (int row = wid; row < NN; row += nw) {
        const int2 be = rb[row];
        const int beg = __builtin_amdgcn_readfirstlane(be.x);
        const int end = __builtin_amdgcn_readfirstlane(be.y);
        const float n = rfl_f(norm[row]);

        float a0 = 0.f, a1 = 0.f;
        for (int b = beg; b < end; b += 8) {
            int sN[8];
            #pragma unroll
            for (int j = 0; j < 8; j++) {
                const int ee = b + j;                   // < NB*CAP+64 (padded alloc)
                const int c = csr[ee];                  // uniform s_load
                int s = __builtin_amdgcn_readfirstlane(c);
                if (ee >= end) s = NN;                  // scalar select -> zero-row
                sN[j] = s;
            }
            u32 u[8];
            #pragma unroll
            for (int j = 0; j < 8; j++) {
                const u32* rp = x + ((size_t)sN[j] << 6);   // SGPR base per edge
                u[j] = rp[lane];                            // coalesced 256B row
            }
            #pragma unroll
            for (int j = 0; j < 8; j++) {
                a0 += __int_as_float((int)(u[j] << 16));
                a1 += __int_as_float((int)(u[j] & 0xFFFF0000u));
            }
        }

        const size_t ri = (size_t)row * 64 + lane;
        u32 o;
        if (!LAST) {
            const float n2 = n * n;
            o = (u32)f2bf(a0 * n2) | ((u32)f2bf(a1 * n2) << 16);
        } else {
            const float inv = rfl_f(invn[row]);
            const u32 v0 = x0[ri];
            const u32 v1 = x1[ri];
            const u32 v2 = x[ri];
            const float s0 = (bf2f((u16)(v0 & 0xFFFFu)) + bf2f((u16)(v1 & 0xFFFFu))
                            + bf2f((u16)(v2 & 0xFFFFu))) * inv + a0 * n;
            const float s1 = (bf2f((u16)(v0 >> 16)) + bf2f((u16)(v1 >> 16))
                            + bf2f((u16)(v2 >> 16))) * inv + a1 * n;
            o = (u32)f2bf(s0 * 0.25f) | ((u32)f2bf(s1 * 0.25f) << 16);
        }
        xnext[ri] = o;
    }
}

// P6: MFMA MLP v4 (best measured) — ct-split layer 1: wave w owns ct
// columns [4w,4w+4), computes them for ALL 64 nodes (4 MFMA per weight
// load). Layer 2: depth-2 ks prefetch. l_s aliases h_s rows [16w,16w+16)
// per wave (reads precede writes in program order; cross-wave phases fenced
// by __syncthreads). v5 (LDS weights, 8 waves/CU) regressed: occupancy/TLP
// carries this kernel, not the weight path.
__global__ __launch_bounds__(256, 4) void mlp_mfma_k(
    const u16* __restrict__ ys, const u16* __restrict__ pw1,
    const float* __restrict__ B1, const u16* __restrict__ pw2,
    const float* __restrict__ B2, float* __restrict__ out, int N)
{
    __shared__ __align__(16) u16 h_s[MT * HPAD];        // 33792 B, l_s aliased in
    const int t = threadIdx.x;
    const int w = t >> 6, lane = t & 63;
    const int quad = lane >> 4, m = lane & 15;
    const int node0 = blockIdx.x * MT;
    float* const lw = (float*)((char*)h_s + (size_t)w * 16 * HPAD * 2); // wave-local l

    // A-fragments for ALL 64 nodes (4 groups of 16)
    bf16x8 av[4][4];                                    // [g][ks], 64 VGPR
    #pragma unroll
    for (int g = 0; g < 4; g++) {
        int node = node0 + g * 16 + m;
        if (node > N - 1) node = N - 1;
        #pragma unroll
        for (int ks = 0; ks < 4; ks++)
            av[g][ks] = *(const bf16x8*)(ys + (size_t)node * IND + ks * 32 + quad * 8);
    }

    // ---- layer 1: wave w -> ct in [4w, 4w+4), depth-2 wb prefetch ----
    const u16* const pwl = pw1 + (size_t)lane * 8;
    const int ct0 = w * 4;
    bf16x8 wb[2][4];
    #pragma unroll
    for (int ks = 0; ks < 4; ks++)
        wb[0][ks] = *(const bf16x8*)(pwl + (size_t)((ct0 * 4 + ks) * 64) * 8);
    #pragma unroll
    for (int ct2 = 0; ct2 < 4; ct2++) {                 // ct2 compile-time: static idx
        const int ct = ct0 + ct2;
        if (ct2 + 1 < 4) {
            #pragma unroll
            for (int ks = 0; ks < 4; ks++)
                wb[(ct2 + 1) & 1][ks] =
                    *(const bf16x8*)(pwl + (size_t)(((ct + 1) * 4 + ks) * 64) * 8);
        }
        const int cs = ct2 & 1;
        f32x4 acc[4];
        #pragma unroll
        for (int g = 0; g < 4; g++) acc[g] = (f32x4){ 0.f, 0.f, 0.f, 0.f };
        #pragma unroll
        for (int ks = 0; ks < 4; ks++) {
            #pragma unroll
            for (int g = 0; g < 4; g++)                 // 4-way independent MFMA per load
                acc[g] = __builtin_amdgcn_mfma_f32_16x16x32_bf16(av[g][ks], wb[cs][ks], acc[g], 0, 0, 0);
        }
        const float b1c = B1[ct * 16 + m];
        #pragma unroll
        for (int g = 0; g < 4; g++) {
            #pragma unroll
            for (int r = 0; r < 4; r++) {
                const float hv = fmaxf(acc[g][r] + b1c, 0.0f);
                h_s[(g * 16 + quad * 4 + r) * HPAD + ct * 16 + m] = f2bf(hv);
            }
        }
    }
    __syncthreads();                                    // h complete (all ct blocks)

    // ---- layer 2: wave w -> node group w, depth-2 prefetch over ks ----
    const u16* const pw2l = pw2 + (size_t)lane * 8;
    f32x4 acc2[3];
    #pragma unroll
    for (int ct = 0; ct < 3; ct++) acc2[ct] = (f32x4){ 0.f, 0.f, 0.f, 0.f };
    bf16x8 w2[3][3];
    #pragma unroll
    for (int ct = 0; ct < 3; ct++) {
        w2[0][ct] = *(const bf16x8*)(pw2l + (size_t)((ct * 8 + 0) * 64) * 8);
        w2[1][ct] = *(const bf16x8*)(pw2l + (size_t)((ct * 8 + 1) * 64) * 8);
    }
    #pragma unroll
    for (int ks = 0; ks < 8; ks++) {                    // ks compile-time: static idx
        if (ks + 2 < 8) {
            const int ns = (ks + 2) % 3;
            #pragma unroll
            for (int ct = 0; ct < 3; ct++)
                w2[ns][ct] = *(const bf16x8*)(pw2l + (size_t)((ct * 8 + ks + 2) * 64) * 8);
        }
        const int cs = ks % 3;
        const bf16x8 a = *(const bf16x8*)&h_s[(w * 16 + m) * HPAD + ks * 32 + quad * 8];
        #pragma unroll
        for (int ct = 0; ct < 3; ct++)
            acc2[ct] = __builtin_amdgcn_mfma_f32_16x16x32_bf16(a, w2[cs][ct], acc2[ct], 0, 0, 0);
    }
    #pragma unroll
    for (int ct = 0; ct < 3; ct++) {
        const int cg = ct * 16 + m;
        const float b2c = (cg < NC) ? B2[cg] : 0.0f;
        #pragma unroll
        for (int r = 0; r < 4; r++)
            lw[(quad * 4 + r) * LPAD + cg] = acc2[ct][r] + b2c;   // after all h reads (lockstep)
    }
    __syncthreads();

    if (t < MT) {
        const int node = node0 + t;
        if (node < N) {
            const float* ln = (const float*)((const char*)h_s + (size_t)(t >> 4) * 16 * HPAD * 2)
                              + (t & 15) * LPAD;
            float mx = -1e30f;
            #pragma unroll
            for (int c = 0; c < NC; c++) mx = fmaxf(mx, ln[c]);
            float s = 0.0f;
            #pragma unroll
            for (int c = 0; c < NC; c++) s += __expf(ln[c] - mx);
            const float lse = mx + __logf(s);
            float4* o = (float4*)(out + (size_t)node * NC);
            #pragma unroll
            for (int c4 = 0; c4 < NC / 4; c4++) {
                float4 v;
                v.x = ln[c4 * 4 + 0] - lse;
                v.y = ln[c4 * 4 + 1] - lse;
                v.z = ln[c4 * 4 + 2] - lse;
                v.w = ln[c4 * 4 + 3] - lse;
                o[c4] = v;
            }
        }
    }
}

extern "C" void kernel_launch(void* const* d_in, const int* in_sizes, int n_in,
                              void* d_out, int out_size, void* d_ws, size_t ws_size,
                              hipStream_t stream) {
    const float* feats = (const float*)d_in[0];
    const int* src = (const int*)d_in[1];
    const int* dst = (const int*)d_in[2];
    const float* W1 = (const float*)d_in[3];
    const float* B1 = (const float*)d_in[4];
    const float* W2 = (const float*)d_in[5];
    const float* B2 = (const float*)d_in[6];
    float* out = (float*)d_out;

    char* base = (char*)d_ws;
    size_t off = 0;
    auto alloc = [&](size_t bytes) -> void* {
        void* p = base + off;
        off += (bytes + 255) & ~(size_t)255;
        return p;
    };
    int*   gcur = (int*)  alloc((size_t)NB * 4);              // zeroed by prep_k
    float* norm = (float*)alloc((size_t)NN * 4);
    float* invn = (float*)alloc((size_t)NN * 4);
    int2*  rb   = (int2*) alloc((size_t)NN * 8);
    u32*   ebuf = (u32*)  alloc(((size_t)NB * CAP + 64) * 4); // bins -> final CSR
    u16*   pw1  = (u16*)  alloc((size_t)16 * 4 * 64 * 8 * 2);
    u16*   pw2  = (u16*)  alloc((size_t)3 * 8 * 64 * 8 * 2);
    u32*   zF   = (u32*)  alloc((size_t)(NN + 1) * (IND / 2) * 4);
    u32*   zA   = (u32*)  alloc((size_t)(NN + 1) * (IND / 2) * 4);
    u32*   zB   = (u32*)  alloc((size_t)(NN + 1) * (IND / 2) * 4);
    u32*   ys   = (u32*)  alloc((size_t)NN * (IND / 2) * 4);

    prep_k<<<22, 256, 0, stream>>>(W1, W2, pw1, pw2, gcur);
    bin_k<<<256, 256, 0, stream>>>(src, dst, gcur, ebuf);
    build_k<<<NB, 256, 0, stream>>>(gcur, ebuf, rb, norm, invn);
    conv_k<<<2048, 256, 0, stream>>>((const float4*)feats, norm,
                                     (uint2*)zF, (uint2*)zA, (uint2*)zB);

    spmm_k<0><<<SGRID, 256, 0, stream>>>(zF, zA, nullptr, nullptr, rb, (const int*)ebuf, norm, invn);
    spmm_k<0><<<SGRID, 256, 0, stream>>>(zA, zB, nullptr, nullptr, rb, (const int*)ebuf, norm, invn);
    spmm_k<1><<<SGRID, 256, 0, stream>>>(zB, ys, zF, zA, rb, (const int*)ebuf, norm, invn);

    const int mgrid = (NN + MT - 1) / MT;
    mlp_mfma_k<<<mgrid, 256, 0, stream>>>((const u16*)ys, pw1, B1, pw2, B2, out, NN);
}